// Round 1
// baseline (305.770 us; speedup 1.0000x reference)
//
#include <hip/hip_runtime.h>
#include <math.h>

#define NNODES 10000
#define NEDGES 100000
#define EPW 8  // edges per wave in edge kernel

// ---------------- compile-time Clebsch-Gordan (port of reference) ----------------
struct Cplx { double re, im; };

constexpr double cfact(int n){ double r=1.0; for(int i=2;i<=n;++i) r*=i; return r; }

constexpr double csqrt_(double x){
  if (x<=0.0) return 0.0;
  double g = x<1.0 ? 1.0 : x;
  for (int it=0; it<64; ++it){ double ng = 0.5*(g + x/g); if (ng==g) break; g = ng; }
  return g;
}

constexpr double cg_coeff(int j1,int m1,int j2,int m2,int j3,int m3){
  if (m1+m2!=m3) return 0.0;
  int lo = j1>j2 ? j1-j2 : j2-j1;
  if (j3<lo || j3>j1+j2) return 0.0;
  if (m1<-j1||m1>j1||m2<-j2||m2>j2||m3<-j3||m3>j3) return 0.0;
  double pre = csqrt_((2.0*j3+1.0)*cfact(j1+j2-j3)*cfact(j1-j2+j3)*cfact(-j1+j2+j3)/cfact(j1+j2+j3+1));
  pre *= csqrt_(cfact(j1+m1)*cfact(j1-m1)*cfact(j2+m2)*cfact(j2-m2)*cfact(j3+m3)*cfact(j3-m3));
  double s = 0.0;
  for (int k=0;k<=j1+j2+j3;++k){
    int d0=j1+j2-j3-k, d1=j1-m1-k, d2=j2+m2-k, d3=j3-j2+m1+k, d4=j3-j1-m2+k;
    if (d0<0||d1<0||d2<0||d3<0||d4<0) continue;
    double term = 1.0/(cfact(k)*cfact(d0)*cfact(d1)*cfact(d2)*cfact(d3)*cfact(d4));
    s += (k&1) ? -term : term;
  }
  return pre*s;
}

constexpr Cplx uent(int l,int a,int i){
  const double s = 0.70710678118654752440;
  int ma = a - l;
  if (ma==0) { if (i==l) return Cplx{1.0,0.0}; return Cplx{0.0,0.0}; }
  if (ma>0){
    int m = ma; double sg = (m&1) ? -1.0 : 1.0;
    if (i==l+m) return Cplx{sg*s, 0.0};
    if (i==l-m) return Cplx{s, 0.0};
    return Cplx{0.0,0.0};
  }
  int m = -ma; double sg = (m&1) ? -1.0 : 1.0;
  if (i==l+m) return Cplx{0.0, -sg*s};
  if (i==l-m) return Cplx{0.0, s};
  return Cplx{0.0,0.0};
}

constexpr double real_cg_entry(int l1,int l2,int l3,int a,int b,int c){
  double acc = 0.0;
  int ii0 = a, ii1 = 2*l1-a;
  int jj0 = b, jj1 = 2*l2-b;
  for (int x=0;x<2;++x){
    int i = (x==0)? ii0 : ii1;
    if (x==1 && ii1==ii0) break;
    Cplx u1 = uent(l1,a,i); if (u1.re==0.0 && u1.im==0.0) continue;
    for (int y=0;y<2;++y){
      int j = (y==0)? jj0 : jj1;
      if (y==1 && jj1==jj0) break;
      Cplx u2 = uent(l2,b,j); if (u2.re==0.0 && u2.im==0.0) continue;
      int k = (i-l1)+(j-l2)+l3;
      if (k<0 || k>2*l3) continue;
      Cplx u3 = uent(l3,c,k); if (u3.re==0.0 && u3.im==0.0) continue;
      double cg = cg_coeff(l1,i-l1,l2,j-l2,l3,k-l3);
      if (cg==0.0) continue;
      double pr = u1.re*u2.re - u1.im*u2.im;
      double pi = u1.re*u2.im + u1.im*u2.re;
      acc += (pr*u3.re + pi*u3.im) * cg;  // Re((u1*u2)*conj(u3))*cg
    }
  }
  return acc;
}

struct CGT { float v[5][5][5]; };
constexpr CGT make_cg(int l1,int l2,int l3){
  CGT t{};
  for (int a=0;a<2*l1+1;++a)
    for (int b=0;b<2*l2+1;++b)
      for (int c=0;c<2*l3+1;++c)
        t.v[a][b][c] = (float)real_cg_entry(l1,l2,l3,a,b,c);
  return t;
}

// ---------------- device helpers ----------------
__device__ __forceinline__ float rdlane(float v, int l){
  return __int_as_float(__builtin_amdgcn_readlane(__float_as_int(v), l));
}
__device__ __forceinline__ float silu_(float x){ return x / (1.0f + __expf(-x)); }

// t[d] = sum_{a,b} CG[a][b][d]*sp[a]*g[b];  msg[d] += rl*t[d]
template<int L1,int L2,int L3>
__device__ __forceinline__ void tp_accum(const float* sp, const float* g, float rl, float* msg){
  constexpr CGT T = make_cg(L1,L2,L3);
  constexpr int NA = 2*L1+1, NB = 2*L2+1, ND = 2*L3+1;
  float t[ND];
#pragma unroll
  for (int d=0; d<ND; ++d) t[d] = 0.f;
#pragma unroll
  for (int b=0;b<NB;++b){
#pragma unroll
    for (int d=0; d<ND; ++d){
      float u = 0.f; bool any = false;
#pragma unroll
      for (int a=0;a<NA;++a){
        const float cg = T.v[a][b][d];
        if (cg != 0.f){ u = fmaf(cg, sp[a], u); any = true; }
      }
      if (any) t[d] = fmaf(u, g[b], t[d]);
    }
  }
#pragma unroll
  for (int d=0;d<ND;++d) msg[d] = fmaf(rl, t[d], msg[d]);
}

// out[d] += w * sum_{a,b} CG[a][b][d]*X[a]*Y[b]
template<int L1,int L2,int L3>
__device__ __forceinline__ void sc_accum(const float* X, const float* Y, float w, float* out){
  constexpr CGT T = make_cg(L1,L2,L3);
  constexpr int NA = 2*L1+1, NB = 2*L2+1, ND = 2*L3+1;
#pragma unroll
  for (int d=0;d<ND;++d){
    float s = 0.f;
#pragma unroll
    for (int a=0;a<NA;++a){
#pragma unroll
      for (int b=0;b<NB;++b){
        const float cg = T.v[a][b][d];
        if (cg != 0.f) s = fmaf(cg*X[a], Y[b], s);
      }
    }
    out[d] = fmaf(w, s, out[d]);
  }
}

// ---------------- kernel 1: h1p = per-irrep h1 @ W_lin_in * 1/sqrt(K) ----------------
__global__ void __launch_bounds__(64) k_lin_in(const float* __restrict__ h1,
                                               const float* __restrict__ W,
                                               float* __restrict__ h1p){
  const int n = blockIdx.x;
  const int d = threadIdx.x;
  const float* row = h1 + (long)n*576;
  float acc[9];
#pragma unroll
  for (int i=0;i<9;++i) acc[i] = 0.f;
  for (int c=0;c<64;++c){
    const float w0 = W[c*64 + d];
    const float w1 = W[4096 + c*64 + d];
    const float w2 = W[8192 + c*64 + d];
    acc[0] = fmaf(row[c], w0, acc[0]);
#pragma unroll
    for (int m=0;m<3;++m) acc[1+m] = fmaf(row[64+m*64+c], w1, acc[1+m]);
#pragma unroll
    for (int m=0;m<5;++m) acc[4+m] = fmaf(row[256+m*64+c], w2, acc[4+m]);
  }
  float* o = h1p + (long)n*576;
  o[d] = acc[0]*0.125f;
#pragma unroll
  for (int m=0;m<3;++m) o[64+m*64+d] = acc[1+m]*0.125f;
#pragma unroll
  for (int m=0;m<5;++m) o[256+m*64+d] = acc[4+m]*0.125f;
}

// ---------------- kernel 2: edge kernel (radial MLP fused + TP + atomic scatter) ----------------
__global__ void __launch_bounds__(64) k_edge(const int* __restrict__ sender,
                                             const int* __restrict__ receiver,
                                             const float* __restrict__ ele,
                                             const float* __restrict__ sph,
                                             const float* __restrict__ h1p,
                                             const float* __restrict__ W0, const float* __restrict__ b0,
                                             const float* __restrict__ W1, const float* __restrict__ b1,
                                             const float* __restrict__ W2, const float* __restrict__ b2,
                                             const float* __restrict__ W3, const float* __restrict__ b3,
                                             float* __restrict__ A){
  const int lane = threadIdx.x;
  const int j32 = lane & 31;
  const long base = (long)blockIdx.x * EPW;

  // ---- radial MLP: layer0 ----
  float h[EPW];
#pragma unroll
  for (int e8=0;e8<EPW;++e8){
    const float* xr = ele + (base+e8)*8;
    float acc = b0[j32];
#pragma unroll
    for (int i=0;i<8;++i) acc = fmaf(xr[i], W0[i*32+j32], acc);
    h[e8] = silu_(acc);
  }
  // ---- residual layers 1,2 ----
#pragma unroll
  for (int L=0; L<2; ++L){
    const float* Wl = L ? W2 : W1;
    const float* bl = L ? b2 : b1;
    float acc[EPW];
#pragma unroll
    for (int e8=0;e8<EPW;++e8) acc[e8] = bl[j32];
    for (int j=0;j<32;++j){
      const float w = Wl[j*32+j32];
#pragma unroll
      for (int e8=0;e8<EPW;++e8) acc[e8] = fmaf(rdlane(h[e8], j), w, acc[e8]);
    }
#pragma unroll
    for (int e8=0;e8<EPW;++e8) h[e8] += silu_(acc[e8]);
  }
  // ---- final layer -> rl[e8][p] for channel=lane ----
  float rl[EPW][11];
#pragma unroll
  for (int e8=0;e8<EPW;++e8)
#pragma unroll
    for (int p=0;p<11;++p) rl[e8][p] = b3[p*64+lane];
  for (int j=0;j<32;++j){
    float w3v[11];
#pragma unroll
    for (int p=0;p<11;++p) w3v[p] = W3[j*704 + p*64 + lane];
#pragma unroll
    for (int e8=0;e8<EPW;++e8){
      const float hj = rdlane(h[e8], j);
#pragma unroll
      for (int p=0;p<11;++p) rl[e8][p] = fmaf(hj, w3v[p], rl[e8][p]);
    }
  }

  // ---- tensor product + scatter per edge ----
#pragma unroll
  for (int e8=0;e8<EPW;++e8){
    const long e = base + e8;
    const int s = sender[e];
    const int r = receiver[e];
    const float* sp = sph + e*9;
    float spv[9];
#pragma unroll
    for (int i=0;i<9;++i) spv[i] = sp[i];
    const float* hp = h1p + (long)s*576;
    float g0[1], g1[3], g2[5];
    g0[0] = hp[lane];
#pragma unroll
    for (int m=0;m<3;++m) g1[m] = hp[64+m*64+lane];
#pragma unroll
    for (int m=0;m<5;++m) g2[m] = hp[256+m*64+lane];
    float m0[1] = {0.f};
    float m1[3] = {0.f,0.f,0.f};
    float m2[5] = {0.f,0.f,0.f,0.f,0.f};
    // EDGE_PATHS order: (0,0,0),(0,1,1),(0,2,2),(1,0,1),(1,1,0),(1,1,2),(1,2,1),(2,0,2),(2,1,1),(2,2,0),(2,2,2)
    tp_accum<0,0,0>(spv+0, g0, rl[e8][0],  m0);
    tp_accum<0,1,1>(spv+0, g1, rl[e8][1],  m1);
    tp_accum<0,2,2>(spv+0, g2, rl[e8][2],  m2);
    tp_accum<1,0,1>(spv+1, g0, rl[e8][3],  m1);
    tp_accum<1,1,0>(spv+1, g1, rl[e8][4],  m0);
    tp_accum<1,1,2>(spv+1, g1, rl[e8][5],  m2);
    tp_accum<1,2,1>(spv+1, g2, rl[e8][6],  m1);
    tp_accum<2,0,2>(spv+4, g0, rl[e8][7],  m2);
    tp_accum<2,1,1>(spv+4, g1, rl[e8][8],  m1);
    tp_accum<2,2,0>(spv+4, g2, rl[e8][9],  m0);
    tp_accum<2,2,2>(spv+4, g2, rl[e8][10], m2);
    float* Ar = A + (long)r*576;
    atomicAdd(&Ar[lane], m0[0]);
#pragma unroll
    for (int m=0;m<3;++m) atomicAdd(&Ar[64+m*64+lane], m1[m]);
#pragma unroll
    for (int m=0;m<5;++m) atomicAdd(&Ar[256+m*64+lane], m2[m]);
  }
}

// ---------------- kernel 3: node kernel (Amix + symmetric contraction + output linears) ----------------
__global__ void __launch_bounds__(64) k_node(const int* __restrict__ indices,
                                             const float* __restrict__ h1,
                                             const float* __restrict__ A,
                                             const float* __restrict__ Wmix,
                                             const float* __restrict__ w1,
                                             const float* __restrict__ w2,
                                             const float* __restrict__ w3,
                                             const float* __restrict__ Wom,
                                             const float* __restrict__ Woh,
                                             float* __restrict__ out){
  __shared__ float Bsh[4][64];
  const int n = blockIdx.x;
  const int lane = threadIdx.x;
  const int e = indices[n];
  const float* Ar = A + (long)n*576;
  float ax[9];
#pragma unroll
  for (int i=0;i<9;++i) ax[i] = 0.f;
  {
    const float* Wm0 = Wmix + (size_t)(0*10 + e)*4096;
    const float* Wm1 = Wmix + (size_t)(1*10 + e)*4096;
    const float* Wm2 = Wmix + (size_t)(2*10 + e)*4096;
    for (int c=0;c<64;++c){
      const float wv0 = Wm0[c*64+lane];
      const float wv1 = Wm1[c*64+lane];
      const float wv2 = Wm2[c*64+lane];
      ax[0] = fmaf(Ar[c], wv0, ax[0]);
#pragma unroll
      for (int m=0;m<3;++m) ax[1+m] = fmaf(Ar[64+m*64+c], wv1, ax[1+m]);
#pragma unroll
      for (int m=0;m<5;++m) ax[4+m] = fmaf(Ar[256+m*64+c], wv2, ax[4+m]);
    }
  }
  // fold (1/AVG_NEIGH) * MIX_NORM = 0.1 / sqrt(64*10)
#pragma unroll
  for (int i=0;i<9;++i) ax[i] *= 0.0039528470752104741f;

  // symmetric contraction; lane = channel c
  const float* amix0 = ax;
  const float* amix1 = ax+1;
  const float* amix2 = ax+4;
  float w2n[5], w3n[5];
#pragma unroll
  for (int p=0;p<5;++p){
    w2n[p] = w2[(size_t)(e*5+p)*64 + lane];
    w3n[p] = w3[(size_t)(e*5+p)*64 + lane];
  }
  float t20[1] = {0.f}, t21[3] = {0.f,0.f,0.f};
  // DEG2_PATHS: (0,0,0),(1,1,0),(2,2,0),(0,1,1),(1,2,1)
  sc_accum<0,0,0>(amix0, amix0, w2n[0], t20);
  sc_accum<1,1,0>(amix1, amix1, w2n[1], t20);
  sc_accum<2,2,0>(amix2, amix2, w2n[2], t20);
  sc_accum<0,1,1>(amix0, amix1, w2n[3], t21);
  sc_accum<1,2,1>(amix1, amix2, w2n[4], t21);
  float t30[1] = {0.f}, t31[3] = {0.f,0.f,0.f};
  // DEG3_PATHS: (0,0,0),(1,1,0),(0,1,1),(1,0,1),(1,2,1)  (first operand = T2[Lp])
  sc_accum<0,0,0>(t20, amix0, w3n[0], t30);
  sc_accum<1,1,0>(t21, amix1, w3n[1], t30);
  sc_accum<0,1,1>(t20, amix1, w3n[2], t31);
  sc_accum<1,0,1>(t21, amix0, w3n[3], t31);
  sc_accum<1,2,1>(t21, amix2, w3n[4], t31);

  const float w1_0 = w1[(size_t)(e*2+0)*64 + lane];
  const float w1_1 = w1[(size_t)(e*2+1)*64 + lane];
  Bsh[0][lane] = fmaf(w1_0, amix0[0], t20[0] + t30[0]);
#pragma unroll
  for (int m=0;m<3;++m) Bsh[1+m][lane] = fmaf(w1_1, amix1[m], t21[m] + t31[m]);
  __syncthreads();

  // output linears: out = (h1@W_out_h + B@W_out_m) * 1/sqrt(K); lane = d
  const float* hrow = h1 + (long)n*576;
  float o[4];
#pragma unroll
  for (int i=0;i<4;++i) o[i] = 0.f;
  for (int c=0;c<64;++c){
    const float wh0 = Woh[c*64+lane];
    const float wh1 = Woh[4096 + c*64+lane];
    const float wm0 = Wom[c*64+lane];
    const float wm1 = Wom[4096 + c*64+lane];
    o[0] = fmaf(hrow[c], wh0, o[0]);
    o[0] = fmaf(Bsh[0][c], wm0, o[0]);
#pragma unroll
    for (int m=0;m<3;++m){
      o[1+m] = fmaf(hrow[64+m*64+c], wh1, o[1+m]);
      o[1+m] = fmaf(Bsh[1+m][c], wm1, o[1+m]);
    }
  }
  float* orow = out + (long)n*256;
  orow[lane] = o[0]*0.125f;
#pragma unroll
  for (int m=0;m<3;++m) orow[64+m*64+lane] = o[1+m]*0.125f;
}

// ---------------- launch ----------------
extern "C" void kernel_launch(void* const* d_in, const int* in_sizes, int n_in,
                              void* d_out, int out_size, void* d_ws, size_t ws_size,
                              hipStream_t stream){
  const int*   sender   = (const int*)  d_in[0];
  const int*   receiver = (const int*)  d_in[1];
  const int*   indices  = (const int*)  d_in[2];
  // d_in[3] = node_attrs (one-hot) -- equivalent to indices, unused
  const float* node_feat= (const float*)d_in[4];
  const float* ele      = (const float*)d_in[5];
  const float* sph      = (const float*)d_in[6];
  const float* W_lin    = (const float*)d_in[7];
  const float* W0 = (const float*)d_in[8],  *b0 = (const float*)d_in[9];
  const float* W1 = (const float*)d_in[10], *b1 = (const float*)d_in[11];
  const float* W2 = (const float*)d_in[12], *b2 = (const float*)d_in[13];
  const float* W3 = (const float*)d_in[14], *b3 = (const float*)d_in[15];
  const float* Wmix = (const float*)d_in[16];
  const float* w1 = (const float*)d_in[17];
  const float* w2 = (const float*)d_in[18];
  const float* w3 = (const float*)d_in[19];
  const float* Wom = (const float*)d_in[20];
  const float* Woh = (const float*)d_in[21];
  float* out = (float*)d_out;

  float* h1p = (float*)d_ws;                        // 10000*576 floats = 23.04 MB
  float* A   = h1p + (size_t)NNODES*576;            // 10000*576 floats = 23.04 MB

  hipMemsetAsync(A, 0, (size_t)NNODES*576*sizeof(float), stream);
  k_lin_in<<<NNODES, 64, 0, stream>>>(node_feat, W_lin, h1p);
  k_edge<<<NEDGES/EPW, 64, 0, stream>>>(sender, receiver, ele, sph, h1p,
                                        W0,b0,W1,b1,W2,b2,W3,b3, A);
  k_node<<<NNODES, 64, 0, stream>>>(indices, node_feat, A, Wmix, w1, w2, w3, Wom, Woh, out);
}